// Round 6
// baseline (727.940 us; speedup 1.0000x reference)
//
#include <hip/hip_runtime.h>

// N=100000 nodes, E=1600000 edges, D_IN=D_OUT=48.
constexpr int N_NODES = 100000;
constexpr int D = 48;
constexpr int QPR = D / 4;                       // 12 float4 quads per row
constexpr int BNODES = 64;                       // dst-nodes per bucket
constexpr int NBUCK = (N_NODES + BNODES - 1) / BNODES;  // 1563
constexpr int NKEY = NBUCK * 8;                  // 12504 (bucket x chunk-group)
constexpr int NKEY_AL = 12544;                   // padded alloc
constexpr int CHUNK1 = 4096;                     // edges per phase1 block (2^12)
constexpr int LROW = 49;                         // padded LDS row (48 would be 32-way bank conflict)

// ---------------------------------------------------------------------------
// Kernel 1: xw = x @ w   (w staged in LDS; one thread = one float4 of a row)
// ---------------------------------------------------------------------------
__global__ __launch_bounds__(256) void gemm_xw(
    const float* __restrict__ x, const float* __restrict__ w,
    float4* __restrict__ xw) {
  __shared__ float wlds[D * D];
  for (int i = threadIdx.x; i < D * D; i += 256) wlds[i] = w[i];
  __syncthreads();

  int id = blockIdx.x * 256 + threadIdx.x;     // [0, N*12)
  if (id >= N_NODES * QPR) return;
  int row = id / QPR;
  int q   = id - row * QPR;

  const float* xr = x + row * D;
  float4 acc = make_float4(0.f, 0.f, 0.f, 0.f);
#pragma unroll
  for (int k = 0; k < D; ++k) {
    float xv = xr[k];
    float4 wv = *reinterpret_cast<const float4*>(&wlds[k * D + q * 4]);
    acc.x = fmaf(xv, wv.x, acc.x);
    acc.y = fmaf(xv, wv.y, acc.y);
    acc.z = fmaf(xv, wv.z, acc.z);
    acc.w = fmaf(xv, wv.w, acc.w);
  }
  xw[id] = acc;
}

// ---------------------------------------------------------------------------
// Kernel 2: histogram per (bucket, group) sub-key.
// group = (edge_index / CHUNK1) & 7 — must match phase1_fill's block grouping.
// ---------------------------------------------------------------------------
__global__ __launch_bounds__(256) void hist_bucket(
    const int* __restrict__ edst, int* __restrict__ bhist, int ne) {
  int e = blockIdx.x * 256 + threadIdx.x;
  if (e >= ne) return;
  int d = edst[e];
  int g = (e >> 12) & 7;                       // CHUNK1 = 4096 = 2^12
  atomicAdd(&bhist[(d >> 6) * 8 + g], 1);
}

// ---------------------------------------------------------------------------
// Kernel 3: single-block exclusive scan of the 12504 sub-key counts.
// boffs[NKEY] = total; bcursor = working copy for phase1.
// ---------------------------------------------------------------------------
__global__ __launch_bounds__(1024) void bh_scan(
    const int* __restrict__ bhist, int* __restrict__ boffs,
    int* __restrict__ bcursor) {
  __shared__ int tsum[1024];
  const int n = NKEY;
  const int C = (n + 1023) / 1024;             // 13
  int t = threadIdx.x;
  int base = t * C;
  int s = 0;
  for (int k = 0; k < C; ++k) {
    int j = base + k;
    if (j < n) s += bhist[j];
  }
  tsum[t] = s;
  __syncthreads();
#pragma unroll
  for (int off = 1; off < 1024; off <<= 1) {
    int v = (t >= off) ? tsum[t - off] : 0;
    __syncthreads();
    tsum[t] += v;
    __syncthreads();
  }
  int run = tsum[t] - s;                       // exclusive across threads
  for (int k = 0; k < C; ++k) {
    int j = base + k;
    if (j < n) {
      int v = bhist[j];
      boffs[j] = run;
      bcursor[j] = run;
      run += v;
    }
  }
  if (t == 0) boffs[n] = tsum[1023];           // grand total
}

// ---------------------------------------------------------------------------
// Kernel 4: bucket edges into staged[]. Block i owns edges [i*4096,(i+1)*4096)
// and writes only to sub-regions of group (i&7) -> temporally-dense line
// assembly in L2 before writeback.
// Entry packs: x = src (17b) | dstLocal (6b) << 17 ; y = f32 val bits.
// ---------------------------------------------------------------------------
__global__ __launch_bounds__(256) void phase1_fill(
    const int* __restrict__ esrc, const int* __restrict__ edst,
    const float* __restrict__ evals, int* __restrict__ bcursor,
    int2* __restrict__ staged, int ne) {
  int g = blockIdx.x & 7;
  int base = blockIdx.x * CHUNK1;
  for (int k = 0; k < CHUNK1; k += 256) {
    int e = base + k + threadIdx.x;
    if (e >= ne) break;                        // monotone per-thread, safe
    int d = edst[e];
    int key = (d >> 6) * 8 + g;
    int pos = atomicAdd(&bcursor[key], 1);
    int2 en;
    en.x = (esrc[e] & 0x1FFFF) | ((d & 63) << 17);
    en.y = __float_as_int(evals[e]);
    staged[pos] = en;
  }
}

// ---------------------------------------------------------------------------
// Kernel 5: one block per 64-node bucket. Stream the bucket's staged edges,
// gather xw[src] (192B contiguous, 12-deep MLP per thread), accumulate into
// a padded LDS tile via ds_add_f32, then fused bias+relu coalesced write.
// ---------------------------------------------------------------------------
__global__ __launch_bounds__(256) void gather_lds(
    const float4* __restrict__ xw, const int* __restrict__ boffs,
    const int2* __restrict__ staged, const float* __restrict__ bias,
    float4* __restrict__ out) {
  __shared__ float lacc[BNODES * LROW];
  int t = threadIdx.x;
  int b = blockIdx.x;

  for (int i = t; i < BNODES * LROW; i += 256) lacc[i] = 0.f;
  __syncthreads();

  int start = boffs[b * 8];
  int end   = boffs[b * 8 + 8];
  for (int e = start + t; e < end; e += 256) {
    int2 en = staged[e];                       // coalesced
    int src = en.x & 0x1FFFF;
    int dl  = (en.x >> 17) & 63;
    float a = __int_as_float(en.y);
    const float4* row = xw + src * QPR;
    int abase = dl * LROW;
#pragma unroll
    for (int q = 0; q < QPR; ++q) {
      float4 v = row[q];
      atomicAdd(&lacc[abase + q * 4 + 0], a * v.x);
      atomicAdd(&lacc[abase + q * 4 + 1], a * v.y);
      atomicAdd(&lacc[abase + q * 4 + 2], a * v.z);
      atomicAdd(&lacc[abase + q * 4 + 3], a * v.w);
    }
  }
  __syncthreads();

  // write out: 64 nodes x 12 quads = 768 slots, coalesced
  for (int i = t; i < BNODES * QPR; i += 256) {
    int nl = i / QPR;
    int q  = i - nl * QPR;
    int node = b * BNODES + nl;
    if (node >= N_NODES) continue;
    int abase = nl * LROW + q * 4;
    float4 r;
    r.x = fmaxf(lacc[abase + 0] + bias[q * 4 + 0], 0.f);
    r.y = fmaxf(lacc[abase + 1] + bias[q * 4 + 1], 0.f);
    r.z = fmaxf(lacc[abase + 2] + bias[q * 4 + 2], 0.f);
    r.w = fmaxf(lacc[abase + 3] + bias[q * 4 + 3], 0.f);
    out[node * QPR + q] = r;
  }
}

// ---------------------------------------------------------------------------
extern "C" void kernel_launch(void* const* d_in, const int* in_sizes, int n_in,
                              void* d_out, int out_size, void* d_ws, size_t ws_size,
                              hipStream_t stream) {
  const float* x     = (const float*)d_in[0];   // [N, 48]
  const float* w     = (const float*)d_in[1];   // [48, 48]
  const float* b     = (const float*)d_in[2];   // [48]
  const int*   esrc  = (const int*)d_in[3];     // [E]
  const int*   edst  = (const int*)d_in[4];     // [E]
  const float* evals = (const float*)d_in[5];   // [E]
  float* out = (float*)d_out;                   // [N, 48]

  const int ne = in_sizes[3];

  // ---- workspace layout (~32.2 MB) ----
  char* p = (char*)d_ws;
  float4* xw  = (float4*)p;   p += (size_t)N_NODES * D * sizeof(float);  // 19.2MB
  int* bhist  = (int*)p;      p += NKEY_AL * sizeof(int);
  int* boffs  = (int*)p;      p += NKEY_AL * sizeof(int);
  int* bcursor= (int*)p;      p += NKEY_AL * sizeof(int);
  p = (char*)(((uintptr_t)p + 15) & ~(uintptr_t)15);
  int2* staged = (int2*)p;    p += (size_t)ne * sizeof(int2);            // 12.8MB

  // bhist must be zero each call (ws re-poisoned to 0xAA before every launch)
  hipMemsetAsync(bhist, 0, NKEY_AL * sizeof(int), stream);

  gemm_xw<<<(N_NODES * QPR + 255) / 256, 256, 0, stream>>>(x, w, xw);

  hist_bucket<<<(ne + 255) / 256, 256, 0, stream>>>(edst, bhist, ne);
  bh_scan<<<1, 1024, 0, stream>>>(bhist, boffs, bcursor);
  phase1_fill<<<(ne + CHUNK1 - 1) / CHUNK1, 256, 0, stream>>>(
      esrc, edst, evals, bcursor, staged, ne);

  gather_lds<<<NBUCK, 256, 0, stream>>>(xw, boffs, staged, b, (float4*)out);
}